// Round 1
// baseline (849.364 us; speedup 1.0000x reference)
//
#include <hip/hip_runtime.h>
#include <hip/hip_bf16.h>
#include <stdint.h>

#define HIDDEN 2048
#define INTER  1408
#define NE     8
#define NTOK   4096

typedef __attribute__((ext_vector_type(8))) short short8;
typedef __attribute__((ext_vector_type(4))) float f32x4;

typedef const __attribute__((address_space(1))) unsigned char* gp1_t;
typedef __attribute__((address_space(3))) unsigned char* lp3_t;

__device__ __forceinline__ void lds_cp16(const void* g, void* l) {
    __builtin_amdgcn_global_load_lds((gp1_t)g, (lp3_t)l, 16, 0, 0);
}

__device__ __forceinline__ short8 ldfrag(const __hip_bfloat16* p) {
    return *(const short8*)p;
}

// ---------------- fp32 -> bf16 conversion ----------------
__global__ void cvt_kernel(const float* __restrict__ src, __hip_bfloat16* __restrict__ dst, int n) {
    int i = (blockIdx.x * blockDim.x + threadIdx.x) * 4;
    if (i >= n) return;
    float4 v = *(const float4*)(src + i);
    __hip_bfloat162 a = __float22bfloat162_rn(make_float2(v.x, v.y));
    __hip_bfloat162 b = __float22bfloat162_rn(make_float2(v.z, v.w));
    *(__hip_bfloat162*)(dst + i)     = a;
    *(__hip_bfloat162*)(dst + i + 2) = b;
}

// ---------------- router: logits -> top2 -> renormalized weights ----------------
__global__ void router_kernel(const float* __restrict__ x, const float* __restrict__ rw,
                              int* __restrict__ counts, int* __restrict__ topk_e,
                              float* __restrict__ topk_w) {
    int wave = threadIdx.x >> 6;
    int lane = threadIdx.x & 63;
    int t = blockIdx.x * 4 + wave;
    const float* xr = x + (size_t)t * HIDDEN;
    float acc[NE] = {0.f,0.f,0.f,0.f,0.f,0.f,0.f,0.f};
    for (int i = lane; i < HIDDEN; i += 64) {
        float xi = xr[i];
        #pragma unroll
        for (int e = 0; e < NE; ++e) acc[e] += xi * rw[e * HIDDEN + i];
    }
    #pragma unroll
    for (int e = 0; e < NE; ++e) {
        #pragma unroll
        for (int off = 32; off > 0; off >>= 1) acc[e] += __shfl_xor(acc[e], off, 64);
    }
    if (lane == 0) {
        int i1 = 0; float v1 = acc[0];
        for (int e = 1; e < NE; ++e) if (acc[e] > v1) { v1 = acc[e]; i1 = e; }
        int i2 = -1; float v2 = -3.0e38f;
        for (int e = 0; e < NE; ++e) if (e != i1 && acc[e] > v2) { v2 = acc[e]; i2 = e; }
        // renormalized top-2 softmax weights (full softmax denominator cancels)
        float w1 = 1.f / (1.f + expf(v2 - v1));
        float w2 = 1.f - w1;
        topk_e[t * 2 + 0] = i1; topk_e[t * 2 + 1] = i2;
        topk_w[t * 2 + 0] = w1; topk_w[t * 2 + 1] = w2;
        atomicAdd(&counts[i1], 1);
        atomicAdd(&counts[i2], 1);
    }
}

__global__ void scan_kernel(const int* __restrict__ counts, int* __restrict__ offsets,
                            int* __restrict__ cursor) {
    if (threadIdx.x == 0) {
        int s = 0;
        for (int e = 0; e < NE; ++e) { offsets[e] = s; cursor[e] = s; s += counts[e]; }
    }
}

__global__ void scatter_kernel(const int* __restrict__ topk_e, const float* __restrict__ topk_w,
                               int* __restrict__ cursor, int* __restrict__ slot_tid,
                               float* __restrict__ slot_w) {
    int k = blockIdx.x * blockDim.x + threadIdx.x;
    if (k >= NTOK * 2) return;
    int e = topk_e[k];
    int slot = atomicAdd(&cursor[e], 1);
    slot_tid[slot] = k >> 1;
    slot_w[slot]   = topk_w[k];
}

// ---------------- GEMM1: h[slot, 0:1408] = silu(x@gate^T) * (x@up^T) * w ----------------
// block tile: 128 rows(slots) x 64 h-cols; B tile stacks 64 gate rows + 64 up rows.
__global__ __launch_bounds__(256) void gemm1_kernel(
    const __hip_bfloat16* __restrict__ xb,
    const __hip_bfloat16* __restrict__ gub,
    const int* __restrict__ counts, const int* __restrict__ offsets,
    const int* __restrict__ slot_tid, const float* __restrict__ slot_w,
    __hip_bfloat16* __restrict__ h)
{
    const int e  = blockIdx.z;
    const int mt = blockIdx.y;
    const int nt = blockIdx.x;            // 0..21 (1408/64)
    const int count = counts[e];
    if (mt * 128 >= count) return;
    const int off = offsets[e];

    __shared__ __hip_bfloat16 As[128][64];
    __shared__ __hip_bfloat16 Bs[128][64];

    const int tid  = threadIdx.x;
    const int wave = tid >> 6;
    const int lane = tid & 63;

    const __hip_bfloat16* asrc[4];
    const __hip_bfloat16* bsrc[4];
    #pragma unroll
    for (int j = 0; j < 4; ++j) {
        int fs  = j * 256 + tid;          // 0..1023 lane-slots; 8 per row
        int row = fs >> 3;
        int c8  = fs & 7;
        int rg  = mt * 128 + row;
        int rc  = rg < count ? rg : count - 1;
        int tok = slot_tid[off + rc];
        asrc[j] = xb + (size_t)tok * HIDDEN + c8 * 8;
        int grow = (row < 64) ? (nt * 64 + row) : (INTER + nt * 64 + (row - 64));
        bsrc[j] = gub + ((size_t)e * 2 * INTER + grow) * HIDDEN + c8 * 8;
    }

    f32x4 acc[2][8];
    #pragma unroll
    for (int mi = 0; mi < 2; ++mi)
        #pragma unroll
        for (int ni = 0; ni < 8; ++ni) acc[mi][ni] = (f32x4)0.f;

    const int fr = lane & 15;
    const int fk = (lane >> 4) * 8;

    for (int k0 = 0; k0 < HIDDEN; k0 += 64) {
        #pragma unroll
        for (int j = 0; j < 4; ++j) {
            lds_cp16(asrc[j] + k0, (__hip_bfloat16*)As + (j * 256 + tid) * 8);
            lds_cp16(bsrc[j] + k0, (__hip_bfloat16*)Bs + (j * 256 + tid) * 8);
        }
        __syncthreads();
        #pragma unroll
        for (int kk = 0; kk < 64; kk += 32) {
            short8 a0 = ldfrag(&As[wave * 32 +      fr][kk + fk]);
            short8 a1 = ldfrag(&As[wave * 32 + 16 + fr][kk + fk]);
            #pragma unroll
            for (int ni = 0; ni < 8; ++ni) {
                short8 b = ldfrag(&Bs[ni * 16 + fr][kk + fk]);
                acc[0][ni] = __builtin_amdgcn_mfma_f32_16x16x32_bf16(a0, b, acc[0][ni], 0, 0, 0);
                acc[1][ni] = __builtin_amdgcn_mfma_f32_16x16x32_bf16(a1, b, acc[1][ni], 0, 0, 0);
            }
        }
        __syncthreads();
    }

    #pragma unroll
    for (int mi = 0; mi < 2; ++mi) {
        #pragma unroll
        for (int r = 0; r < 4; ++r) {
            int row = wave * 32 + mi * 16 + (lane >> 4) * 4 + r;   // C/D: row=(lane>>4)*4+reg
            int rg  = mt * 128 + row;
            if (rg < count) {
                float wgt = slot_w[off + rg];
                size_t base = (size_t)(off + rg) * INTER + nt * 64;
                #pragma unroll
                for (int ni = 0; ni < 4; ++ni) {
                    float g = acc[mi][ni][r];
                    float u = acc[mi][ni + 4][r];
                    float hv = g / (1.f + __expf(-g)) * u * wgt;
                    h[base + ni * 16 + fr] = __float2bfloat16(hv);
                }
            }
        }
    }
}

// ---------------- GEMM2: out[token, :] += h[slot,:] @ down^T ----------------
__global__ __launch_bounds__(256) void gemm2_kernel(
    const __hip_bfloat16* __restrict__ h,
    const __hip_bfloat16* __restrict__ dnb,
    const int* __restrict__ counts, const int* __restrict__ offsets,
    const int* __restrict__ slot_tid,
    float* __restrict__ out)
{
    const int e  = blockIdx.z;
    const int mt = blockIdx.y;
    const int nt = blockIdx.x;            // 0..15 (2048/128)
    const int count = counts[e];
    if (mt * 128 >= count) return;
    const int off = offsets[e];

    __shared__ __hip_bfloat16 As[128][64];
    __shared__ __hip_bfloat16 Bs[128][64];

    const int tid  = threadIdx.x;
    const int wave = tid >> 6;
    const int lane = tid & 63;

    const __hip_bfloat16* asrc[4];
    const __hip_bfloat16* bsrc[4];
    #pragma unroll
    for (int j = 0; j < 4; ++j) {
        int fs  = j * 256 + tid;
        int row = fs >> 3;
        int c8  = fs & 7;
        // slots beyond count read padded garbage rows (masked at store)
        asrc[j] = h + (size_t)(off + mt * 128 + row) * INTER + c8 * 8;
        bsrc[j] = dnb + ((size_t)e * HIDDEN + nt * 128 + row) * INTER + c8 * 8;
    }

    f32x4 acc[2][8];
    #pragma unroll
    for (int mi = 0; mi < 2; ++mi)
        #pragma unroll
        for (int ni = 0; ni < 8; ++ni) acc[mi][ni] = (f32x4)0.f;

    const int fr = lane & 15;
    const int fk = (lane >> 4) * 8;

    for (int k0 = 0; k0 < INTER; k0 += 64) {
        #pragma unroll
        for (int j = 0; j < 4; ++j) {
            lds_cp16(asrc[j] + k0, (__hip_bfloat16*)As + (j * 256 + tid) * 8);
            lds_cp16(bsrc[j] + k0, (__hip_bfloat16*)Bs + (j * 256 + tid) * 8);
        }
        __syncthreads();
        #pragma unroll
        for (int kk = 0; kk < 64; kk += 32) {
            short8 a0 = ldfrag(&As[wave * 32 +      fr][kk + fk]);
            short8 a1 = ldfrag(&As[wave * 32 + 16 + fr][kk + fk]);
            #pragma unroll
            for (int ni = 0; ni < 8; ++ni) {
                short8 b = ldfrag(&Bs[ni * 16 + fr][kk + fk]);
                acc[0][ni] = __builtin_amdgcn_mfma_f32_16x16x32_bf16(a0, b, acc[0][ni], 0, 0, 0);
                acc[1][ni] = __builtin_amdgcn_mfma_f32_16x16x32_bf16(a1, b, acc[1][ni], 0, 0, 0);
            }
        }
        __syncthreads();
    }

    #pragma unroll
    for (int mi = 0; mi < 2; ++mi) {
        #pragma unroll
        for (int r = 0; r < 4; ++r) {
            int row = wave * 32 + mi * 16 + (lane >> 4) * 4 + r;
            int rg  = mt * 128 + row;
            if (rg < count) {
                int t = slot_tid[off + rg];
                float* orow = out + (size_t)t * HIDDEN + nt * 128;
                #pragma unroll
                for (int ni = 0; ni < 8; ++ni) {
                    atomicAdd(orow + ni * 16 + fr, acc[mi][ni][r]);
                }
            }
        }
    }
}

extern "C" void kernel_launch(void* const* d_in, const int* in_sizes, int n_in,
                              void* d_out, int out_size, void* d_ws, size_t ws_size,
                              hipStream_t stream)
{
    (void)in_sizes; (void)n_in; (void)ws_size;
    const float* x  = (const float*)d_in[0];
    const float* rw = (const float*)d_in[1];
    const float* gu = (const float*)d_in[2];
    const float* dn = (const float*)d_in[3];

    char* p = (char*)d_ws;
    auto take = [&](size_t bytes) { char* r = p; p += (bytes + 255) & ~(size_t)255; return r; };
    __hip_bfloat16* xb  = (__hip_bfloat16*)take((size_t)NTOK * HIDDEN * 2);
    __hip_bfloat16* gub = (__hip_bfloat16*)take((size_t)NE * 2 * INTER * HIDDEN * 2);
    __hip_bfloat16* dnb = (__hip_bfloat16*)take((size_t)NE * HIDDEN * INTER * 2);
    __hip_bfloat16* hbuf= (__hip_bfloat16*)take((size_t)(2 * NTOK + 128) * INTER * 2);
    int*   counts   = (int*)take(64);
    int*   offsets  = (int*)take(64);
    int*   cursor   = (int*)take(64);
    int*   topk_e   = (int*)take((size_t)NTOK * 2 * 4);
    float* topk_w   = (float*)take((size_t)NTOK * 2 * 4);
    int*   slot_tid = (int*)take((size_t)(2 * NTOK + 128) * 4);
    float* slot_w   = (float*)take((size_t)(2 * NTOK + 128) * 4);

    hipMemsetAsync(counts, 0, 64, stream);
    hipMemsetAsync(d_out, 0, (size_t)out_size * sizeof(float), stream);

    {
        int n = NTOK * HIDDEN;
        cvt_kernel<<<dim3((n / 4 + 255) / 256), 256, 0, stream>>>(x, xb, n);
    }
    {
        int n = NE * 2 * INTER * HIDDEN;
        cvt_kernel<<<dim3((n / 4 + 255) / 256), 256, 0, stream>>>(gu, gub, n);
    }
    {
        int n = NE * HIDDEN * INTER;
        cvt_kernel<<<dim3((n / 4 + 255) / 256), 256, 0, stream>>>(dn, dnb, n);
    }

    router_kernel<<<dim3(NTOK / 4), 256, 0, stream>>>(x, rw, counts, topk_e, topk_w);
    scan_kernel<<<dim3(1), 64, 0, stream>>>(counts, offsets, cursor);
    scatter_kernel<<<dim3((NTOK * 2) / 256), 256, 0, stream>>>(topk_e, topk_w, cursor, slot_tid, slot_w);

    gemm1_kernel<<<dim3(INTER / 64, NTOK / 128, NE), 256, 0, stream>>>(
        xb, gub, counts, offsets, slot_tid, slot_w, hbuf);
    gemm2_kernel<<<dim3(HIDDEN / 128, NTOK / 128, NE), 256, 0, stream>>>(
        hbuf, dnb, counts, offsets, slot_tid, (float*)d_out);
}

// Round 2
// 787.747 us; speedup vs baseline: 1.0782x; 1.0782x over previous
//
#include <hip/hip_runtime.h>
#include <hip/hip_bf16.h>
#include <stdint.h>

#define HIDDEN 2048
#define INTER  1408
#define NE     8
#define NTOK   4096

typedef __attribute__((ext_vector_type(8))) short short8;
typedef __attribute__((ext_vector_type(4))) float f32x4;

typedef const __attribute__((address_space(1))) unsigned char* gp1_t;
typedef __attribute__((address_space(3))) unsigned char* lp3_t;

__device__ __forceinline__ void lds_cp16(const void* g, void* l) {
    __builtin_amdgcn_global_load_lds((gp1_t)g, (lp3_t)l, 16, 0, 0);
}

// XOR-swizzled LDS fragment read: row r, column col (col % 8 == 0).
// LDS chunk slot s holds global chunk (s ^ (r&7)); to read global chunk c
// fetch slot (c ^ (r&7)). Spreads the 16-rows-same-column fragment pattern
// across all 32 banks (was a 16-way conflict with the linear layout).
__device__ __forceinline__ short8 ldswz(const __hip_bfloat16 (*S)[64], int r, int col) {
    return *(const short8*)&S[r][(((col >> 3) ^ (r & 7)) << 3)];
}

// ---------------- fp32 -> bf16 conversion ----------------
__global__ void cvt_kernel(const float* __restrict__ src, __hip_bfloat16* __restrict__ dst, int n) {
    int i = (blockIdx.x * blockDim.x + threadIdx.x) * 4;
    if (i >= n) return;
    float4 v = *(const float4*)(src + i);
    __hip_bfloat162 a = __float22bfloat162_rn(make_float2(v.x, v.y));
    __hip_bfloat162 b = __float22bfloat162_rn(make_float2(v.z, v.w));
    *(__hip_bfloat162*)(dst + i)     = a;
    *(__hip_bfloat162*)(dst + i + 2) = b;
}

// ---------------- router: logits -> top2 -> renormalized weights ----------------
__global__ void router_kernel(const float* __restrict__ x, const float* __restrict__ rw,
                              int* __restrict__ counts, int* __restrict__ topk_e,
                              float* __restrict__ topk_w) {
    int wave = threadIdx.x >> 6;
    int lane = threadIdx.x & 63;
    int t = blockIdx.x * 4 + wave;
    const float* xr = x + (size_t)t * HIDDEN;
    float acc[NE] = {0.f,0.f,0.f,0.f,0.f,0.f,0.f,0.f};
    for (int i = lane; i < HIDDEN; i += 64) {
        float xi = xr[i];
        #pragma unroll
        for (int e = 0; e < NE; ++e) acc[e] += xi * rw[e * HIDDEN + i];
    }
    #pragma unroll
    for (int e = 0; e < NE; ++e) {
        #pragma unroll
        for (int off = 32; off > 0; off >>= 1) acc[e] += __shfl_xor(acc[e], off, 64);
    }
    if (lane == 0) {
        int i1 = 0; float v1 = acc[0];
        for (int e = 1; e < NE; ++e) if (acc[e] > v1) { v1 = acc[e]; i1 = e; }
        int i2 = -1; float v2 = -3.0e38f;
        for (int e = 0; e < NE; ++e) if (e != i1 && acc[e] > v2) { v2 = acc[e]; i2 = e; }
        // renormalized top-2 softmax weights (full softmax denominator cancels)
        float w1 = 1.f / (1.f + expf(v2 - v1));
        float w2 = 1.f - w1;
        topk_e[t * 2 + 0] = i1; topk_e[t * 2 + 1] = i2;
        topk_w[t * 2 + 0] = w1; topk_w[t * 2 + 1] = w2;
        atomicAdd(&counts[i1], 1);
        atomicAdd(&counts[i2], 1);
    }
}

__global__ void scan_kernel(const int* __restrict__ counts, int* __restrict__ offsets,
                            int* __restrict__ cursor) {
    if (threadIdx.x == 0) {
        int s = 0;
        for (int e = 0; e < NE; ++e) { offsets[e] = s; cursor[e] = s; s += counts[e]; }
    }
}

__global__ void scatter_kernel(const int* __restrict__ topk_e, const float* __restrict__ topk_w,
                               int* __restrict__ cursor, int* __restrict__ slot_tid,
                               float* __restrict__ slot_w) {
    int k = blockIdx.x * blockDim.x + threadIdx.x;
    if (k >= NTOK * 2) return;
    int e = topk_e[k];
    int slot = atomicAdd(&cursor[e], 1);
    slot_tid[slot] = k >> 1;
    slot_w[slot]   = topk_w[k];
}

// ---------------- GEMM1: h[slot, 0:1408] = silu(x@gate^T) * (x@up^T) * w ----------------
// block tile: 128 rows(slots) x 64 h-cols; B tile stacks 64 gate rows + 64 up rows.
__global__ __launch_bounds__(256) void gemm1_kernel(
    const __hip_bfloat16* __restrict__ xb,
    const __hip_bfloat16* __restrict__ gub,
    const int* __restrict__ counts, const int* __restrict__ offsets,
    const int* __restrict__ slot_tid, const float* __restrict__ slot_w,
    __hip_bfloat16* __restrict__ h)
{
    const int e  = blockIdx.z;
    const int mt = blockIdx.y;
    const int nt = blockIdx.x;            // 0..21 (1408/64)
    const int count = counts[e];
    if (mt * 128 >= count) return;
    const int off = offsets[e];

    __shared__ __hip_bfloat16 As[128][64];
    __shared__ __hip_bfloat16 Bs[128][64];

    const int tid  = threadIdx.x;
    const int wave = tid >> 6;
    const int lane = tid & 63;

    const __hip_bfloat16* asrc[4];
    const __hip_bfloat16* bsrc[4];
    #pragma unroll
    for (int j = 0; j < 4; ++j) {
        int fs  = j * 256 + tid;          // 0..1023 lane-slots; 8 per row
        int row = fs >> 3;
        int c8  = (fs & 7) ^ (row & 7);   // XOR-swizzled source chunk
        int rg  = mt * 128 + row;
        int rc  = rg < count ? rg : count - 1;
        int tok = slot_tid[off + rc];
        asrc[j] = xb + (size_t)tok * HIDDEN + c8 * 8;
        int grow = (row < 64) ? (nt * 64 + row) : (INTER + nt * 64 + (row - 64));
        bsrc[j] = gub + ((size_t)e * 2 * INTER + grow) * HIDDEN + c8 * 8;
    }

    f32x4 acc[2][8];
    #pragma unroll
    for (int mi = 0; mi < 2; ++mi)
        #pragma unroll
        for (int ni = 0; ni < 8; ++ni) acc[mi][ni] = (f32x4)0.f;

    const int fr = lane & 15;
    const int fk = (lane >> 4) * 8;

    for (int k0 = 0; k0 < HIDDEN; k0 += 64) {
        #pragma unroll
        for (int j = 0; j < 4; ++j) {
            lds_cp16(asrc[j] + k0, (__hip_bfloat16*)As + (j * 256 + tid) * 8);
            lds_cp16(bsrc[j] + k0, (__hip_bfloat16*)Bs + (j * 256 + tid) * 8);
        }
        __syncthreads();
        #pragma unroll
        for (int kk = 0; kk < 64; kk += 32) {
            short8 a0 = ldswz(As, wave * 32 +      fr, kk + fk);
            short8 a1 = ldswz(As, wave * 32 + 16 + fr, kk + fk);
            #pragma unroll
            for (int ni = 0; ni < 8; ++ni) {
                short8 b = ldswz(Bs, ni * 16 + fr, kk + fk);
                acc[0][ni] = __builtin_amdgcn_mfma_f32_16x16x32_bf16(a0, b, acc[0][ni], 0, 0, 0);
                acc[1][ni] = __builtin_amdgcn_mfma_f32_16x16x32_bf16(a1, b, acc[1][ni], 0, 0, 0);
            }
        }
        __syncthreads();
    }

    #pragma unroll
    for (int mi = 0; mi < 2; ++mi) {
        #pragma unroll
        for (int r = 0; r < 4; ++r) {
            int row = wave * 32 + mi * 16 + (lane >> 4) * 4 + r;   // C/D: row=(lane>>4)*4+reg
            int rg  = mt * 128 + row;
            if (rg < count) {
                float wgt = slot_w[off + rg];
                size_t base = (size_t)(off + rg) * INTER + nt * 64;
                #pragma unroll
                for (int ni = 0; ni < 4; ++ni) {
                    float g = acc[mi][ni][r];
                    float u = acc[mi][ni + 4][r];
                    float hv = g / (1.f + __expf(-g)) * u * wgt;
                    h[base + ni * 16 + fr] = __float2bfloat16(hv);
                }
            }
        }
    }
}

// ---------------- GEMM2: out[token, :] += h[slot,:] @ down^T ----------------
__global__ __launch_bounds__(256) void gemm2_kernel(
    const __hip_bfloat16* __restrict__ h,
    const __hip_bfloat16* __restrict__ dnb,
    const int* __restrict__ counts, const int* __restrict__ offsets,
    const int* __restrict__ slot_tid,
    float* __restrict__ out)
{
    const int e  = blockIdx.z;
    const int mt = blockIdx.y;
    const int nt = blockIdx.x;            // 0..15 (2048/128)
    const int count = counts[e];
    if (mt * 128 >= count) return;
    const int off = offsets[e];

    __shared__ __hip_bfloat16 As[128][64];
    __shared__ __hip_bfloat16 Bs[128][64];

    const int tid  = threadIdx.x;
    const int wave = tid >> 6;
    const int lane = tid & 63;

    const __hip_bfloat16* asrc[4];
    const __hip_bfloat16* bsrc[4];
    #pragma unroll
    for (int j = 0; j < 4; ++j) {
        int fs  = j * 256 + tid;
        int row = fs >> 3;
        int c8  = (fs & 7) ^ (row & 7);   // XOR-swizzled source chunk
        // slots beyond count read padded garbage rows (masked at store)
        asrc[j] = h + (size_t)(off + mt * 128 + row) * INTER + c8 * 8;
        bsrc[j] = dnb + ((size_t)e * HIDDEN + nt * 128 + row) * INTER + c8 * 8;
    }

    f32x4 acc[2][8];
    #pragma unroll
    for (int mi = 0; mi < 2; ++mi)
        #pragma unroll
        for (int ni = 0; ni < 8; ++ni) acc[mi][ni] = (f32x4)0.f;

    const int fr = lane & 15;
    const int fk = (lane >> 4) * 8;

    for (int k0 = 0; k0 < INTER; k0 += 64) {
        #pragma unroll
        for (int j = 0; j < 4; ++j) {
            lds_cp16(asrc[j] + k0, (__hip_bfloat16*)As + (j * 256 + tid) * 8);
            lds_cp16(bsrc[j] + k0, (__hip_bfloat16*)Bs + (j * 256 + tid) * 8);
        }
        __syncthreads();
        #pragma unroll
        for (int kk = 0; kk < 64; kk += 32) {
            short8 a0 = ldswz(As, wave * 32 +      fr, kk + fk);
            short8 a1 = ldswz(As, wave * 32 + 16 + fr, kk + fk);
            #pragma unroll
            for (int ni = 0; ni < 8; ++ni) {
                short8 b = ldswz(Bs, ni * 16 + fr, kk + fk);
                acc[0][ni] = __builtin_amdgcn_mfma_f32_16x16x32_bf16(a0, b, acc[0][ni], 0, 0, 0);
                acc[1][ni] = __builtin_amdgcn_mfma_f32_16x16x32_bf16(a1, b, acc[1][ni], 0, 0, 0);
            }
        }
        __syncthreads();
    }

    #pragma unroll
    for (int mi = 0; mi < 2; ++mi) {
        #pragma unroll
        for (int r = 0; r < 4; ++r) {
            int row = wave * 32 + mi * 16 + (lane >> 4) * 4 + r;
            int rg  = mt * 128 + row;
            if (rg < count) {
                int t = slot_tid[off + rg];
                float* orow = out + (size_t)t * HIDDEN + nt * 128;
                #pragma unroll
                for (int ni = 0; ni < 8; ++ni) {
                    atomicAdd(orow + ni * 16 + fr, acc[mi][ni][r]);
                }
            }
        }
    }
}

extern "C" void kernel_launch(void* const* d_in, const int* in_sizes, int n_in,
                              void* d_out, int out_size, void* d_ws, size_t ws_size,
                              hipStream_t stream)
{
    (void)in_sizes; (void)n_in; (void)ws_size;
    const float* x  = (const float*)d_in[0];
    const float* rw = (const float*)d_in[1];
    const float* gu = (const float*)d_in[2];
    const float* dn = (const float*)d_in[3];

    char* p = (char*)d_ws;
    auto take = [&](size_t bytes) { char* r = p; p += (bytes + 255) & ~(size_t)255; return r; };
    __hip_bfloat16* xb  = (__hip_bfloat16*)take((size_t)NTOK * HIDDEN * 2);
    __hip_bfloat16* gub = (__hip_bfloat16*)take((size_t)NE * 2 * INTER * HIDDEN * 2);
    __hip_bfloat16* dnb = (__hip_bfloat16*)take((size_t)NE * HIDDEN * INTER * 2);
    __hip_bfloat16* hbuf= (__hip_bfloat16*)take((size_t)(2 * NTOK + 128) * INTER * 2);
    int*   counts   = (int*)take(64);
    int*   offsets  = (int*)take(64);
    int*   cursor   = (int*)take(64);
    int*   topk_e   = (int*)take((size_t)NTOK * 2 * 4);
    float* topk_w   = (float*)take((size_t)NTOK * 2 * 4);
    int*   slot_tid = (int*)take((size_t)(2 * NTOK + 128) * 4);
    float* slot_w   = (float*)take((size_t)(2 * NTOK + 128) * 4);

    hipMemsetAsync(counts, 0, 64, stream);
    hipMemsetAsync(d_out, 0, (size_t)out_size * sizeof(float), stream);

    {
        int n = NTOK * HIDDEN;
        cvt_kernel<<<dim3((n / 4 + 255) / 256), 256, 0, stream>>>(x, xb, n);
    }
    {
        int n = NE * 2 * INTER * HIDDEN;
        cvt_kernel<<<dim3((n / 4 + 255) / 256), 256, 0, stream>>>(gu, gub, n);
    }
    {
        int n = NE * HIDDEN * INTER;
        cvt_kernel<<<dim3((n / 4 + 255) / 256), 256, 0, stream>>>(dn, dnb, n);
    }

    router_kernel<<<dim3(NTOK / 4), 256, 0, stream>>>(x, rw, counts, topk_e, topk_w);
    scan_kernel<<<dim3(1), 64, 0, stream>>>(counts, offsets, cursor);
    scatter_kernel<<<dim3((NTOK * 2) / 256), 256, 0, stream>>>(topk_e, topk_w, cursor, slot_tid, slot_w);

    gemm1_kernel<<<dim3(INTER / 64, NTOK / 128, NE), 256, 0, stream>>>(
        xb, gub, counts, offsets, slot_tid, slot_w, hbuf);
    gemm2_kernel<<<dim3(HIDDEN / 128, NTOK / 128, NE), 256, 0, stream>>>(
        hbuf, dnb, counts, offsets, slot_tid, (float*)d_out);
}

// Round 3
// 730.340 us; speedup vs baseline: 1.1630x; 1.0786x over previous
//
#include <hip/hip_runtime.h>
#include <hip/hip_bf16.h>
#include <stdint.h>

#define HIDDEN 2048
#define INTER  1408
#define NE     8
#define NTOK   4096
#define MAXTILES 72   // sum ceil(count_e/128) <= 8192/128 + 8

typedef __attribute__((ext_vector_type(8))) short short8;
typedef __attribute__((ext_vector_type(4))) float f32x4;

typedef const __attribute__((address_space(1))) unsigned char* gp1_t;
typedef __attribute__((address_space(3))) unsigned char* lp3_t;

__device__ __forceinline__ void lds_cp16(const void* g, void* l) {
    __builtin_amdgcn_global_load_lds((gp1_t)g, (lp3_t)l, 16, 0, 0);
}

// XOR-swizzled LDS fragment read (conflict-free; verified round 2: conflicts -> 0)
__device__ __forceinline__ short8 ldswz(const __hip_bfloat16 (*S)[64], int r, int col) {
    return *(const short8*)&S[r][(((col >> 3) ^ (r & 7)) << 3)];
}

__device__ __forceinline__ float bf2f(short s) {
    union { float f; unsigned u; } u; u.u = ((unsigned)(unsigned short)s) << 16; return u.f;
}

// ---------------- fused fp32 -> bf16 conversion (x, gate_up, down in one grid) --------
#define C0 (NTOK * HIDDEN / 4)          // 2,097,152 float4 chunks
#define C1 (NE * 2 * INTER * HIDDEN / 4) // 11,534,336
#define C2 (NE * HIDDEN * INTER / 4)     // 5,767,168
__global__ void cvt_all_kernel(const float* __restrict__ x, const float* __restrict__ gu,
                               const float* __restrict__ dn,
                               __hip_bfloat16* __restrict__ xb, __hip_bfloat16* __restrict__ gub,
                               __hip_bfloat16* __restrict__ dnb) {
    long c = (long)blockIdx.x * blockDim.x + threadIdx.x;
    const float* s; __hip_bfloat16* d; long o;
    if (c < C0)           { s = x;  d = xb;  o = c; }
    else if (c < C0 + C1) { s = gu; d = gub; o = c - C0; }
    else                  { s = dn; d = dnb; o = c - C0 - C1; }
    o *= 4;
    float4 v = *(const float4*)(s + o);
    *(__hip_bfloat162*)(d + o)     = __float22bfloat162_rn(make_float2(v.x, v.y));
    *(__hip_bfloat162*)(d + o + 2) = __float22bfloat162_rn(make_float2(v.z, v.w));
}

// ---------------- router: logits -> top2 -> renormalized weights ----------------
__global__ void router_kernel(const float* __restrict__ x, const float* __restrict__ rw,
                              int* __restrict__ counts, int* __restrict__ topk_e,
                              float* __restrict__ topk_w) {
    int wave = threadIdx.x >> 6;
    int lane = threadIdx.x & 63;
    int t = blockIdx.x * 4 + wave;
    const float* xr = x + (size_t)t * HIDDEN;
    float acc[NE] = {0.f,0.f,0.f,0.f,0.f,0.f,0.f,0.f};
    for (int i = lane; i < HIDDEN; i += 64) {
        float xi = xr[i];
        #pragma unroll
        for (int e = 0; e < NE; ++e) acc[e] += xi * rw[e * HIDDEN + i];
    }
    #pragma unroll
    for (int e = 0; e < NE; ++e) {
        #pragma unroll
        for (int off = 32; off > 0; off >>= 1) acc[e] += __shfl_xor(acc[e], off, 64);
    }
    if (lane == 0) {
        int i1 = 0; float v1 = acc[0];
        for (int e = 1; e < NE; ++e) if (acc[e] > v1) { v1 = acc[e]; i1 = e; }
        int i2 = -1; float v2 = -3.0e38f;
        for (int e = 0; e < NE; ++e) if (e != i1 && acc[e] > v2) { v2 = acc[e]; i2 = e; }
        float w1 = 1.f / (1.f + expf(v2 - v1));   // renormalized top-2 softmax
        float w2 = 1.f - w1;
        topk_e[t * 2 + 0] = i1; topk_e[t * 2 + 1] = i2;
        topk_w[t * 2 + 0] = w1; topk_w[t * 2 + 1] = w2;
        atomicAdd(&counts[i1], 1);
        atomicAdd(&counts[i2], 1);
    }
}

__global__ void scan_kernel(const int* __restrict__ counts, int* __restrict__ offsets,
                            int* __restrict__ cursor, int* __restrict__ tiles,
                            int* __restrict__ n_tiles) {
    if (threadIdx.x == 0) {
        int s = 0, nt = 0;
        for (int e = 0; e < NE; ++e) {
            offsets[e] = s; cursor[e] = s;
            int c = counts[e]; s += c;
            for (int mt = 0; mt * 128 < c; ++mt) tiles[nt++] = (e << 16) | mt;
        }
        n_tiles[0] = nt;
    }
}

__global__ void scatter_kernel(const int* __restrict__ topk_e, const float* __restrict__ topk_w,
                               int* __restrict__ cursor, int* __restrict__ slot_tid,
                               float* __restrict__ slot_w, int* __restrict__ tok2slot) {
    int k = blockIdx.x * blockDim.x + threadIdx.x;
    if (k >= NTOK * 2) return;
    int e = topk_e[k];
    int slot = atomicAdd(&cursor[e], 1);
    slot_tid[slot] = k >> 1;
    slot_w[slot]   = topk_w[k];
    tok2slot[k]    = slot;
}

// ---------------- GEMM1: h[slot, :] = silu(x@gate^T) * (x@up^T) * w ----------------
// 128 slots x 64 h-cols per block; B tile: rows [wn*64, wn*64+31] = gate of h-cols
// nt*64 + wn*32 + 0..31, rows [wn*64+32, +63] = up of the same h-cols (keeps the
// SwiGLU gate/up pair lane-local under 2x2 wave tiling).
__global__ __launch_bounds__(256) void gemm1_kernel(
    const __hip_bfloat16* __restrict__ xb,
    const __hip_bfloat16* __restrict__ gub,
    const int* __restrict__ counts, const int* __restrict__ offsets,
    const int* __restrict__ tiles, const int* __restrict__ n_tiles,
    const int* __restrict__ slot_tid, const float* __restrict__ slot_w,
    __hip_bfloat16* __restrict__ h)
{
    const int ti = blockIdx.y;
    if (ti >= n_tiles[0]) return;
    const int tile = tiles[ti];
    const int e  = tile >> 16;
    const int mt = tile & 0xffff;
    const int nt = blockIdx.x;            // 0..21
    const int count = counts[e];
    const int off = offsets[e];

    __shared__ __hip_bfloat16 As[128][64];
    __shared__ __hip_bfloat16 Bs[128][64];

    const int tid  = threadIdx.x;
    const int wave = tid >> 6;
    const int lane = tid & 63;
    const int wm = wave >> 1, wn = wave & 1;

    const __hip_bfloat16* asrc[4];
    const __hip_bfloat16* bsrc[4];
    #pragma unroll
    for (int j = 0; j < 4; ++j) {
        int fs  = j * 256 + tid;          // 1024 chunk-slots, 8 per row
        int row = fs >> 3;
        int c8  = (fs & 7) ^ (row & 7);   // XOR-swizzled source chunk
        int rg  = mt * 128 + row;
        int rc  = rg < count ? rg : count - 1;
        int tok = slot_tid[off + rc];
        asrc[j] = xb + (size_t)tok * HIDDEN + c8 * 8;
        int within = row & 63, sel = within >> 5, idx = within & 31;
        int hc  = nt * 64 + (row >> 6) * 32 + idx;
        int grow = sel ? (INTER + hc) : hc;
        bsrc[j] = gub + ((size_t)e * 2 * INTER + grow) * HIDDEN + c8 * 8;
    }

    f32x4 acc[4][4];
    #pragma unroll
    for (int mi = 0; mi < 4; ++mi)
        #pragma unroll
        for (int ni = 0; ni < 4; ++ni) acc[mi][ni] = (f32x4)0.f;

    const int fr = lane & 15;
    const int fk = (lane >> 4) * 8;

    for (int k0 = 0; k0 < HIDDEN; k0 += 64) {
        #pragma unroll
        for (int j = 0; j < 4; ++j) {
            lds_cp16(asrc[j] + k0, (__hip_bfloat16*)As + (j * 256 + tid) * 8);
            lds_cp16(bsrc[j] + k0, (__hip_bfloat16*)Bs + (j * 256 + tid) * 8);
        }
        __syncthreads();
        #pragma unroll
        for (int kk = 0; kk < 64; kk += 32) {
            short8 a[4], b[4];
            #pragma unroll
            for (int mi = 0; mi < 4; ++mi) a[mi] = ldswz(As, wm * 64 + mi * 16 + fr, kk + fk);
            #pragma unroll
            for (int ni = 0; ni < 4; ++ni) b[ni] = ldswz(Bs, wn * 64 + ni * 16 + fr, kk + fk);
            #pragma unroll
            for (int mi = 0; mi < 4; ++mi)
                #pragma unroll
                for (int ni = 0; ni < 4; ++ni)
                    acc[mi][ni] = __builtin_amdgcn_mfma_f32_16x16x32_bf16(a[mi], b[ni], acc[mi][ni], 0, 0, 0);
        }
        __syncthreads();
    }

    #pragma unroll
    for (int mi = 0; mi < 4; ++mi) {
        #pragma unroll
        for (int r = 0; r < 4; ++r) {
            int row = wm * 64 + mi * 16 + (lane >> 4) * 4 + r;   // C/D: row=(lane>>4)*4+reg
            int rg  = mt * 128 + row;
            if (rg < count) {
                float wgt = slot_w[off + rg];
                size_t base = (size_t)(off + rg) * INTER + nt * 64 + wn * 32;
                #pragma unroll
                for (int ni = 0; ni < 2; ++ni) {
                    float g = acc[mi][ni][r];
                    float u = acc[mi][ni + 2][r];
                    float hv = g / (1.f + __expf(-g)) * u * wgt;
                    h[base + ni * 16 + fr] = __float2bfloat16(hv);
                }
            }
        }
    }
}

// ---------------- GEMM2: eo[slot, :] = h[slot,:] @ down^T (plain stores) ----------------
__global__ __launch_bounds__(256) void gemm2_kernel(
    const __hip_bfloat16* __restrict__ h,
    const __hip_bfloat16* __restrict__ dnb,
    const int* __restrict__ counts, const int* __restrict__ offsets,
    const int* __restrict__ tiles, const int* __restrict__ n_tiles,
    __hip_bfloat16* __restrict__ eo)
{
    const int ti = blockIdx.y;
    if (ti >= n_tiles[0]) return;
    const int tile = tiles[ti];
    const int e  = tile >> 16;
    const int mt = tile & 0xffff;
    const int nt = blockIdx.x;            // 0..15
    const int count = counts[e];
    const int off = offsets[e];

    __shared__ __hip_bfloat16 As[128][64];
    __shared__ __hip_bfloat16 Bs[128][64];

    const int tid  = threadIdx.x;
    const int wave = tid >> 6;
    const int lane = tid & 63;
    const int wm = wave >> 1, wn = wave & 1;

    const __hip_bfloat16* asrc[4];
    const __hip_bfloat16* bsrc[4];
    #pragma unroll
    for (int j = 0; j < 4; ++j) {
        int fs  = j * 256 + tid;
        int row = fs >> 3;
        int c8  = (fs & 7) ^ (row & 7);
        asrc[j] = h + (size_t)(off + mt * 128 + row) * INTER + c8 * 8;
        bsrc[j] = dnb + ((size_t)e * HIDDEN + nt * 128 + row) * INTER + c8 * 8;
    }

    f32x4 acc[4][4];
    #pragma unroll
    for (int mi = 0; mi < 4; ++mi)
        #pragma unroll
        for (int ni = 0; ni < 4; ++ni) acc[mi][ni] = (f32x4)0.f;

    const int fr = lane & 15;
    const int fk = (lane >> 4) * 8;

    for (int k0 = 0; k0 < INTER; k0 += 64) {
        #pragma unroll
        for (int j = 0; j < 4; ++j) {
            lds_cp16(asrc[j] + k0, (__hip_bfloat16*)As + (j * 256 + tid) * 8);
            lds_cp16(bsrc[j] + k0, (__hip_bfloat16*)Bs + (j * 256 + tid) * 8);
        }
        __syncthreads();
        #pragma unroll
        for (int kk = 0; kk < 64; kk += 32) {
            short8 a[4], b[4];
            #pragma unroll
            for (int mi = 0; mi < 4; ++mi) a[mi] = ldswz(As, wm * 64 + mi * 16 + fr, kk + fk);
            #pragma unroll
            for (int ni = 0; ni < 4; ++ni) b[ni] = ldswz(Bs, wn * 64 + ni * 16 + fr, kk + fk);
            #pragma unroll
            for (int mi = 0; mi < 4; ++mi)
                #pragma unroll
                for (int ni = 0; ni < 4; ++ni)
                    acc[mi][ni] = __builtin_amdgcn_mfma_f32_16x16x32_bf16(a[mi], b[ni], acc[mi][ni], 0, 0, 0);
        }
        __syncthreads();
    }

    #pragma unroll
    for (int mi = 0; mi < 4; ++mi) {
        #pragma unroll
        for (int r = 0; r < 4; ++r) {
            int row = wm * 64 + mi * 16 + (lane >> 4) * 4 + r;
            int rg  = mt * 128 + row;
            if (rg < count) {
                size_t base = (size_t)(off + rg) * HIDDEN + nt * 128 + wn * 64;
                #pragma unroll
                for (int ni = 0; ni < 4; ++ni)
                    eo[base + ni * 16 + fr] = __float2bfloat16(acc[mi][ni][r]);
            }
        }
    }
}

// ---------------- combine: out[t] = eo[slot1] + eo[slot2] ----------------
__global__ void combine_kernel(const __hip_bfloat16* __restrict__ eo,
                               const int* __restrict__ tok2slot,
                               float* __restrict__ out) {
    int idx = blockIdx.x * blockDim.x + threadIdx.x;   // one per 8 output floats
    int t = idx >> 8;                                  // 2048/8 = 256 chunks/token
    int c = (idx & 255) * 8;
    int s1 = tok2slot[t * 2], s2 = tok2slot[t * 2 + 1];
    short8 v1 = *(const short8*)(eo + (size_t)s1 * HIDDEN + c);
    short8 v2 = *(const short8*)(eo + (size_t)s2 * HIDDEN + c);
    float4 o0, o1;
    o0.x = bf2f(v1[0]) + bf2f(v2[0]); o0.y = bf2f(v1[1]) + bf2f(v2[1]);
    o0.z = bf2f(v1[2]) + bf2f(v2[2]); o0.w = bf2f(v1[3]) + bf2f(v2[3]);
    o1.x = bf2f(v1[4]) + bf2f(v2[4]); o1.y = bf2f(v1[5]) + bf2f(v2[5]);
    o1.z = bf2f(v1[6]) + bf2f(v2[6]); o1.w = bf2f(v1[7]) + bf2f(v2[7]);
    float* op = out + (size_t)t * HIDDEN + c;
    *(float4*)op = o0;
    *(float4*)(op + 4) = o1;
}

extern "C" void kernel_launch(void* const* d_in, const int* in_sizes, int n_in,
                              void* d_out, int out_size, void* d_ws, size_t ws_size,
                              hipStream_t stream)
{
    (void)in_sizes; (void)n_in; (void)ws_size; (void)out_size;
    const float* x  = (const float*)d_in[0];
    const float* rw = (const float*)d_in[1];
    const float* gu = (const float*)d_in[2];
    const float* dn = (const float*)d_in[3];

    char* p = (char*)d_ws;
    auto take = [&](size_t bytes) { char* r = p; p += (bytes + 255) & ~(size_t)255; return r; };
    __hip_bfloat16* xb  = (__hip_bfloat16*)take((size_t)NTOK * HIDDEN * 2);
    __hip_bfloat16* gub = (__hip_bfloat16*)take((size_t)NE * 2 * INTER * HIDDEN * 2);
    __hip_bfloat16* dnb = (__hip_bfloat16*)take((size_t)NE * HIDDEN * INTER * 2);
    __hip_bfloat16* hbuf= (__hip_bfloat16*)take((size_t)(2 * NTOK + 128) * INTER * 2);
    int*   counts   = (int*)take(64);
    int*   offsets  = (int*)take(64);
    int*   cursor   = (int*)take(64);
    int*   ntile    = (int*)take(64);
    int*   tiles    = (int*)take(MAXTILES * 4);
    int*   topk_e   = (int*)take((size_t)NTOK * 2 * 4);
    float* topk_w   = (float*)take((size_t)NTOK * 2 * 4);
    int*   slot_tid = (int*)take((size_t)(2 * NTOK + 128) * 4);
    float* slot_w   = (float*)take((size_t)(2 * NTOK + 128) * 4);
    int*   tok2slot = (int*)take((size_t)NTOK * 2 * 4);
    // eo aliases gub scratch: gub is dead after gemm1, eo (33.5 MB) < gub (92.3 MB)
    __hip_bfloat16* eo = gub;

    hipMemsetAsync(counts, 0, 64, stream);

    cvt_all_kernel<<<dim3((C0 + C1 + C2) / 256), 256, 0, stream>>>(x, gu, dn, xb, gub, dnb);

    router_kernel<<<dim3(NTOK / 4), 256, 0, stream>>>(x, rw, counts, topk_e, topk_w);
    scan_kernel<<<dim3(1), 64, 0, stream>>>(counts, offsets, cursor, tiles, ntile);
    scatter_kernel<<<dim3((NTOK * 2) / 256), 256, 0, stream>>>(topk_e, topk_w, cursor,
                                                               slot_tid, slot_w, tok2slot);

    gemm1_kernel<<<dim3(INTER / 64, MAXTILES), 256, 0, stream>>>(
        xb, gub, counts, offsets, tiles, ntile, slot_tid, slot_w, hbuf);
    gemm2_kernel<<<dim3(HIDDEN / 128, MAXTILES), 256, 0, stream>>>(
        hbuf, dnb, counts, offsets, tiles, ntile, eo);
    combine_kernel<<<dim3(NTOK * HIDDEN / 8 / 256), 256, 0, stream>>>(
        eo, tok2slot, (float*)d_out);
}

// Round 4
// 691.060 us; speedup vs baseline: 1.2291x; 1.0568x over previous
//
#include <hip/hip_runtime.h>
#include <hip/hip_bf16.h>
#include <stdint.h>

#define HIDDEN 2048
#define INTER  1408
#define NE     8
#define NTOK   4096
#define MAXTILES 72

typedef __attribute__((ext_vector_type(8))) short short8;
typedef __attribute__((ext_vector_type(16))) float f32x16;

typedef const __attribute__((address_space(1))) unsigned char* gp1_t;
typedef __attribute__((address_space(3))) unsigned char* lp3_t;

__device__ __forceinline__ void lds_cp16(const void* g, void* l) {
    __builtin_amdgcn_global_load_lds((gp1_t)g, (lp3_t)l, 16, 0, 0);
}

// XOR-swizzled LDS fragment read (conflict-free; verified round 2: conflicts -> 0)
__device__ __forceinline__ short8 ldswz(const __hip_bfloat16 (*S)[64], int r, int col) {
    return *(const short8*)&S[r][(((col >> 3) ^ (r & 7)) << 3)];
}

__device__ __forceinline__ float bf2f(short s) {
    union { float f; unsigned u; } u; u.u = ((unsigned)(unsigned short)s) << 16; return u.f;
}

// ---------------- fp32 -> bf16 weight conversion (gate_up + down fused) --------
#define C1 (NE * 2 * INTER * HIDDEN / 4) // 11,534,336 float4 chunks
#define C2 (NE * HIDDEN * INTER / 4)     // 5,767,168
__global__ void cvt_w_kernel(const float* __restrict__ gu, const float* __restrict__ dn,
                             __hip_bfloat16* __restrict__ gub, __hip_bfloat16* __restrict__ dnb) {
    long c = (long)blockIdx.x * blockDim.x + threadIdx.x;
    const float* s; __hip_bfloat16* d; long o;
    if (c < C1) { s = gu; d = gub; o = c; }
    else        { s = dn; d = dnb; o = c - C1; }
    o *= 4;
    float4 v = *(const float4*)(s + o);
    *(__hip_bfloat162*)(d + o)     = __float22bfloat162_rn(make_float2(v.x, v.y));
    *(__hip_bfloat162*)(d + o + 2) = __float22bfloat162_rn(make_float2(v.z, v.w));
}

// ---------------- router: logits -> top2 -> weights; also emits x in bf16 ----------
__global__ void router_kernel(const float* __restrict__ x, const float* __restrict__ rw,
                              int* __restrict__ counts, int* __restrict__ topk_e,
                              float* __restrict__ topk_w, __hip_bfloat16* __restrict__ xb) {
    int wave = threadIdx.x >> 6;
    int lane = threadIdx.x & 63;
    int t = blockIdx.x * 4 + wave;
    const float4* xr = (const float4*)(x + (size_t)t * HIDDEN);
    __hip_bfloat16* xbr = xb + (size_t)t * HIDDEN;
    float acc[NE] = {0.f,0.f,0.f,0.f,0.f,0.f,0.f,0.f};
    #pragma unroll
    for (int c = lane; c < HIDDEN / 4; c += 64) {       // 8 iterations
        float4 v = xr[c];
        *(__hip_bfloat162*)(xbr + c * 4)     = __float22bfloat162_rn(make_float2(v.x, v.y));
        *(__hip_bfloat162*)(xbr + c * 4 + 2) = __float22bfloat162_rn(make_float2(v.z, v.w));
        #pragma unroll
        for (int e = 0; e < NE; ++e) {
            float4 w = ((const float4*)(rw + e * HIDDEN))[c];
            acc[e] += v.x * w.x + v.y * w.y + v.z * w.z + v.w * w.w;
        }
    }
    #pragma unroll
    for (int e = 0; e < NE; ++e) {
        #pragma unroll
        for (int off = 32; off > 0; off >>= 1) acc[e] += __shfl_xor(acc[e], off, 64);
    }
    if (lane == 0) {
        int i1 = 0; float v1 = acc[0];
        for (int e = 1; e < NE; ++e) if (acc[e] > v1) { v1 = acc[e]; i1 = e; }
        int i2 = -1; float v2 = -3.0e38f;
        for (int e = 0; e < NE; ++e) if (e != i1 && acc[e] > v2) { v2 = acc[e]; i2 = e; }
        float w1 = 1.f / (1.f + expf(v2 - v1));   // renormalized top-2 softmax
        float w2 = 1.f - w1;
        topk_e[t * 2 + 0] = i1; topk_e[t * 2 + 1] = i2;
        topk_w[t * 2 + 0] = w1; topk_w[t * 2 + 1] = w2;
        atomicAdd(&counts[i1], 1);
        atomicAdd(&counts[i2], 1);
    }
}

__global__ void scan_kernel(const int* __restrict__ counts, int* __restrict__ offsets,
                            int* __restrict__ cursor, int* __restrict__ tiles,
                            int* __restrict__ n_tiles) {
    if (threadIdx.x == 0) {
        int s = 0, nt = 0;
        for (int e = 0; e < NE; ++e) {
            offsets[e] = s; cursor[e] = s;
            int c = counts[e]; s += c;
            for (int mt = 0; mt * 128 < c; ++mt) tiles[nt++] = (e << 16) | mt;
        }
        n_tiles[0] = nt;
    }
}

__global__ void scatter_kernel(const int* __restrict__ topk_e, const float* __restrict__ topk_w,
                               int* __restrict__ cursor, int* __restrict__ slot_tid,
                               float* __restrict__ slot_w, int* __restrict__ tok2slot) {
    int k = blockIdx.x * blockDim.x + threadIdx.x;
    if (k >= NTOK * 2) return;
    int e = topk_e[k];
    int slot = atomicAdd(&cursor[e], 1);
    slot_tid[slot] = k >> 1;
    slot_w[slot]   = topk_w[k];
    tok2slot[k]    = slot;
}

// ---------------- GEMM1: h[slot, :] = silu(x@gate^T) * (x@up^T) * w ----------------
// 128 slots x 64 h-cols; 32x32x16 MFMA, 2x2 waves. B tile rows: [g0..31 of hc 0..31,
// u of same, g of hc 32..63, u of same] so each wave's gate/up pair is register-local.
__global__ __launch_bounds__(256) void gemm1_kernel(
    const __hip_bfloat16* __restrict__ xb,
    const __hip_bfloat16* __restrict__ gub,
    const int* __restrict__ counts, const int* __restrict__ offsets,
    const int* __restrict__ tiles, const int* __restrict__ n_tiles,
    const int* __restrict__ slot_tid, const float* __restrict__ slot_w,
    __hip_bfloat16* __restrict__ h)
{
    const int ti = blockIdx.y;
    if (ti >= n_tiles[0]) return;
    const int tile = tiles[ti];
    const int e  = tile >> 16;
    const int mt = tile & 0xffff;
    const int nt = blockIdx.x;            // 0..21
    const int count = counts[e];
    const int off = offsets[e];

    __shared__ __hip_bfloat16 As[128][64];
    __shared__ __hip_bfloat16 Bs[128][64];

    const int tid  = threadIdx.x;
    const int wave = tid >> 6;
    const int lane = tid & 63;
    const int wm = wave >> 1, wn = wave & 1;
    const int l31 = lane & 31;
    const int fk  = (lane >> 5) * 8;      // A/B operand: k = (lane>>5)*8 + j

    const __hip_bfloat16* asrc[4];
    const __hip_bfloat16* bsrc[4];
    #pragma unroll
    for (int j = 0; j < 4; ++j) {
        int fs  = j * 256 + tid;          // 1024 chunk-slots, 8 per row
        int row = fs >> 3;
        int c8  = (fs & 7) ^ (row & 7);   // XOR-swizzled source chunk
        int rg  = mt * 128 + row;
        int rc  = rg < count ? rg : count - 1;
        int tok = slot_tid[off + rc];
        asrc[j] = xb + (size_t)tok * HIDDEN + c8 * 8;
        int within = row & 63, sel = within >> 5, idx = within & 31;
        int hc  = nt * 64 + (row >> 6) * 32 + idx;
        int grow = sel ? (INTER + hc) : hc;
        bsrc[j] = gub + ((size_t)e * 2 * INTER + grow) * HIDDEN + c8 * 8;
    }

    f32x16 accg[2], accu[2];
    #pragma unroll
    for (int mi = 0; mi < 2; ++mi) { accg[mi] = (f32x16)0.f; accu[mi] = (f32x16)0.f; }

    for (int k0 = 0; k0 < HIDDEN; k0 += 64) {
        #pragma unroll
        for (int j = 0; j < 4; ++j) {
            lds_cp16(asrc[j] + k0, (__hip_bfloat16*)As + (j * 256 + tid) * 8);
            lds_cp16(bsrc[j] + k0, (__hip_bfloat16*)Bs + (j * 256 + tid) * 8);
        }
        __syncthreads();
        #pragma unroll
        for (int kk = 0; kk < 64; kk += 16) {
            short8 a0 = ldswz(As, wm * 64 +      l31, kk + fk);
            short8 a1 = ldswz(As, wm * 64 + 32 + l31, kk + fk);
            short8 bg = ldswz(Bs, wn * 64 +      l31, kk + fk);
            short8 bu = ldswz(Bs, wn * 64 + 32 + l31, kk + fk);
            accg[0] = __builtin_amdgcn_mfma_f32_32x32x16_bf16(a0, bg, accg[0], 0, 0, 0);
            accg[1] = __builtin_amdgcn_mfma_f32_32x32x16_bf16(a1, bg, accg[1], 0, 0, 0);
            accu[0] = __builtin_amdgcn_mfma_f32_32x32x16_bf16(a0, bu, accu[0], 0, 0, 0);
            accu[1] = __builtin_amdgcn_mfma_f32_32x32x16_bf16(a1, bu, accu[1], 0, 0, 0);
        }
        __syncthreads();
    }

    // C/D: col = lane&31, row = (reg&3) + 8*(reg>>2) + 4*(lane>>5)
    #pragma unroll
    for (int mi = 0; mi < 2; ++mi) {
        #pragma unroll
        for (int reg = 0; reg < 16; ++reg) {
            int row = wm * 64 + mi * 32 + (reg & 3) + 8 * (reg >> 2) + 4 * (lane >> 5);
            int rg  = mt * 128 + row;
            if (rg < count) {
                float wgt = slot_w[off + rg];
                float g = accg[mi][reg];
                float u = accu[mi][reg];
                float hv = g / (1.f + __expf(-g)) * u * wgt;
                h[(size_t)(off + rg) * INTER + nt * 64 + wn * 32 + l31] = __float2bfloat16(hv);
            }
        }
    }
}

// ---------------- GEMM2: eo[slot, :] = h[slot,:] @ down^T (plain stores) ----------------
__global__ __launch_bounds__(256) void gemm2_kernel(
    const __hip_bfloat16* __restrict__ h,
    const __hip_bfloat16* __restrict__ dnb,
    const int* __restrict__ counts, const int* __restrict__ offsets,
    const int* __restrict__ tiles, const int* __restrict__ n_tiles,
    __hip_bfloat16* __restrict__ eo)
{
    const int ti = blockIdx.y;
    if (ti >= n_tiles[0]) return;
    const int tile = tiles[ti];
    const int e  = tile >> 16;
    const int mt = tile & 0xffff;
    const int nt = blockIdx.x;            // 0..15
    const int count = counts[e];
    const int off = offsets[e];

    __shared__ __hip_bfloat16 As[128][64];
    __shared__ __hip_bfloat16 Bs[128][64];

    const int tid  = threadIdx.x;
    const int wave = tid >> 6;
    const int lane = tid & 63;
    const int wm = wave >> 1, wn = wave & 1;
    const int l31 = lane & 31;
    const int fk  = (lane >> 5) * 8;

    const __hip_bfloat16* asrc[4];
    const __hip_bfloat16* bsrc[4];
    #pragma unroll
    for (int j = 0; j < 4; ++j) {
        int fs  = j * 256 + tid;
        int row = fs >> 3;
        int c8  = (fs & 7) ^ (row & 7);
        asrc[j] = h + (size_t)(off + mt * 128 + row) * INTER + c8 * 8;
        bsrc[j] = dnb + ((size_t)e * HIDDEN + nt * 128 + row) * INTER + c8 * 8;
    }

    f32x16 acc[2][2];
    #pragma unroll
    for (int mi = 0; mi < 2; ++mi)
        #pragma unroll
        for (int nj = 0; nj < 2; ++nj) acc[mi][nj] = (f32x16)0.f;

    for (int k0 = 0; k0 < INTER; k0 += 64) {
        #pragma unroll
        for (int j = 0; j < 4; ++j) {
            lds_cp16(asrc[j] + k0, (__hip_bfloat16*)As + (j * 256 + tid) * 8);
            lds_cp16(bsrc[j] + k0, (__hip_bfloat16*)Bs + (j * 256 + tid) * 8);
        }
        __syncthreads();
        #pragma unroll
        for (int kk = 0; kk < 64; kk += 16) {
            short8 a0 = ldswz(As, wm * 64 +      l31, kk + fk);
            short8 a1 = ldswz(As, wm * 64 + 32 + l31, kk + fk);
            short8 b0 = ldswz(Bs, wn * 64 +      l31, kk + fk);
            short8 b1 = ldswz(Bs, wn * 64 + 32 + l31, kk + fk);
            acc[0][0] = __builtin_amdgcn_mfma_f32_32x32x16_bf16(a0, b0, acc[0][0], 0, 0, 0);
            acc[0][1] = __builtin_amdgcn_mfma_f32_32x32x16_bf16(a0, b1, acc[0][1], 0, 0, 0);
            acc[1][0] = __builtin_amdgcn_mfma_f32_32x32x16_bf16(a1, b0, acc[1][0], 0, 0, 0);
            acc[1][1] = __builtin_amdgcn_mfma_f32_32x32x16_bf16(a1, b1, acc[1][1], 0, 0, 0);
        }
        __syncthreads();
    }

    #pragma unroll
    for (int mi = 0; mi < 2; ++mi) {
        #pragma unroll
        for (int reg = 0; reg < 16; ++reg) {
            int row = wm * 64 + mi * 32 + (reg & 3) + 8 * (reg >> 2) + 4 * (lane >> 5);
            int rg  = mt * 128 + row;
            if (rg < count) {
                size_t base = (size_t)(off + rg) * HIDDEN + nt * 128 + wn * 64;
                eo[base +      l31] = __float2bfloat16(acc[mi][0][reg]);
                eo[base + 32 + l31] = __float2bfloat16(acc[mi][1][reg]);
            }
        }
    }
}

// ---------------- combine: out[t] = eo[slot1] + eo[slot2] ----------------
__global__ void combine_kernel(const __hip_bfloat16* __restrict__ eo,
                               const int* __restrict__ tok2slot,
                               float* __restrict__ out) {
    int idx = blockIdx.x * blockDim.x + threadIdx.x;   // one per 8 output floats
    int t = idx >> 8;                                  // 2048/8 = 256 chunks/token
    int c = (idx & 255) * 8;
    int s1 = tok2slot[t * 2], s2 = tok2slot[t * 2 + 1];
    short8 v1 = *(const short8*)(eo + (size_t)s1 * HIDDEN + c);
    short8 v2 = *(const short8*)(eo + (size_t)s2 * HIDDEN + c);
    float4 o0, o1;
    o0.x = bf2f(v1[0]) + bf2f(v2[0]); o0.y = bf2f(v1[1]) + bf2f(v2[1]);
    o0.z = bf2f(v1[2]) + bf2f(v2[2]); o0.w = bf2f(v1[3]) + bf2f(v2[3]);
    o1.x = bf2f(v1[4]) + bf2f(v2[4]); o1.y = bf2f(v1[5]) + bf2f(v2[5]);
    o1.z = bf2f(v1[6]) + bf2f(v2[6]); o1.w = bf2f(v1[7]) + bf2f(v2[7]);
    float* op = out + (size_t)t * HIDDEN + c;
    *(float4*)op = o0;
    *(float4*)(op + 4) = o1;
}

extern "C" void kernel_launch(void* const* d_in, const int* in_sizes, int n_in,
                              void* d_out, int out_size, void* d_ws, size_t ws_size,
                              hipStream_t stream)
{
    (void)in_sizes; (void)n_in; (void)ws_size; (void)out_size;
    const float* x  = (const float*)d_in[0];
    const float* rw = (const float*)d_in[1];
    const float* gu = (const float*)d_in[2];
    const float* dn = (const float*)d_in[3];

    char* p = (char*)d_ws;
    auto take = [&](size_t bytes) { char* r = p; p += (bytes + 255) & ~(size_t)255; return r; };
    __hip_bfloat16* xb  = (__hip_bfloat16*)take((size_t)NTOK * HIDDEN * 2);
    __hip_bfloat16* gub = (__hip_bfloat16*)take((size_t)NE * 2 * INTER * HIDDEN * 2);
    __hip_bfloat16* dnb = (__hip_bfloat16*)take((size_t)NE * HIDDEN * INTER * 2);
    __hip_bfloat16* hbuf= (__hip_bfloat16*)take((size_t)(2 * NTOK + 128) * INTER * 2);
    int*   counts   = (int*)take(64);
    int*   offsets  = (int*)take(64);
    int*   cursor   = (int*)take(64);
    int*   ntile    = (int*)take(64);
    int*   tiles    = (int*)take(MAXTILES * 4);
    int*   topk_e   = (int*)take((size_t)NTOK * 2 * 4);
    float* topk_w   = (float*)take((size_t)NTOK * 2 * 4);
    int*   slot_tid = (int*)take((size_t)(2 * NTOK + 128) * 4);
    float* slot_w   = (float*)take((size_t)(2 * NTOK + 128) * 4);
    int*   tok2slot = (int*)take((size_t)NTOK * 2 * 4);
    // eo aliases gub scratch: gub is dead after gemm1, eo (33.5 MB) < gub (92.3 MB)
    __hip_bfloat16* eo = gub;

    hipMemsetAsync(counts, 0, 64, stream);

    cvt_w_kernel<<<dim3((C1 + C2) / 256), 256, 0, stream>>>(gu, dn, gub, dnb);

    router_kernel<<<dim3(NTOK / 4), 256, 0, stream>>>(x, rw, counts, topk_e, topk_w, xb);
    scan_kernel<<<dim3(1), 64, 0, stream>>>(counts, offsets, cursor, tiles, ntile);
    scatter_kernel<<<dim3((NTOK * 2) / 256), 256, 0, stream>>>(topk_e, topk_w, cursor,
                                                               slot_tid, slot_w, tok2slot);

    gemm1_kernel<<<dim3(INTER / 64, MAXTILES), 256, 0, stream>>>(
        xb, gub, counts, offsets, tiles, ntile, slot_tid, slot_w, hbuf);
    gemm2_kernel<<<dim3(HIDDEN / 128, MAXTILES), 256, 0, stream>>>(
        hbuf, dnb, counts, offsets, tiles, ntile, eo);
    combine_kernel<<<dim3(NTOK * HIDDEN / 8 / 256), 256, 0, stream>>>(
        eo, tok2slot, (float*)d_out);
}